// Round 7
// baseline (506.876 us; speedup 1.0000x reference)
//
#include <hip/hip_runtime.h>
#include <math.h>

#define N_TOK 8192
#define DIM   1024
#define NE    8
#define NR    16
#define NO    3072
#define OUT_ELEMS (N_TOK * NO)   // 25165824
#define TOKS  32                 // tokens per kF block
#define KC    64                 // K-chunk
#define NCH   16                 // 1024/64

__device__ __forceinline__ float softplusf(float z) {
  return z > 0.f ? z + log1pf(expf(-z)) : log1pf(expf(z));
}
__device__ __forceinline__ float ncdf(float z) {
  return 0.5f * erfcf(-z * 0.70710678118654752f);
}

#define FMA4(A, S, W) { (A).x = fmaf((S),(W).x,(A).x); (A).y = fmaf((S),(W).y,(A).y); \
                        (A).z = fmaf((S),(W).z,(A).z); (A).w = fmaf((S),(W).w,(A).w); }
#define DOT4ACC(ACC, X, W) ACC = fmaf((X).x,(W).x, fmaf((X).y,(W).y, fmaf((X).z,(W).z, fmaf((X).w,(W).w,(ACC)))))
#define Z4 make_float4(0.f,0.f,0.f,0.f)

typedef __attribute__((address_space(3))) void LDSV;
typedef const __attribute__((address_space(1))) void GLBV;
__device__ __forceinline__ void stage16(const void* g, void* l) {
  __builtin_amdgcn_global_load_lds((GLBV*)g, (LDSV*)l, 16, 0, 0);
}
__device__ __forceinline__ void waitvm0() {
  asm volatile("s_waitcnt vmcnt(0)" ::: "memory");
}

// LDS layout (bytes): xb[2][8192] | wA[2][32768] | wG[2][4096] | lgS 2560
#define XB_OFF  0
#define WA_OFF  16384
#define WG_OFF  (16384 + 65536)
#define LG_OFF  (16384 + 65536 + 8192)
#define KF_SMEM (LG_OFF + 2560 + 128)

// ---------------------------------------------------------------------------
// kF: fused gating + h.  M=8192 N=144 K=1024 f32 GEMM, kE-style.
// 256 blocks x 32 tokens. Per K-chunk(64): stage x(8KB)+aT(32KB)+wg/wn(4KB)
// via global_load_lds (pre-swizzled sources, linear LDS dest), dbuf, vmcnt(0)
// only after compute. Phase A: thread=(tokg8,colq32) -> 4tok x 4cols of
// h_all (128 cols = 8 experts x 16 r). Phase B: thread=(tok32,og8) -> 2
// gating cols. Epilogue: gating math (t<32), write h for selected expert.
// ---------------------------------------------------------------------------
__global__ __launch_bounds__(256) void kF(const float* __restrict__ x,
    const float* __restrict__ wg, const float* __restrict__ wn,
    const float* __restrict__ la, const float* __restrict__ nz,
    int* __restrict__ eid, float* __restrict__ part, float* __restrict__ h) {
  extern __shared__ char smem[];
  float* lgS = (float*)(smem + LG_OFF);           // [32][20]
  int* eid_sh = (int*)(smem + LG_OFF + 2560);     // [32]
  int t = threadIdx.x;
  int n0 = blockIdx.x * TOKS;
  // phase A ids
  int tokg = t >> 5, colq = t & 31;
  // phase B ids
  int tokB = t & 31, og = t >> 5;
  float4 acc0 = Z4, acc1 = Z4, acc2 = Z4, acc3 = Z4;   // [ti] x 4 cols
  float ga = 0.f, gb = 0.f;                            // gating cols 2og,2og+1

  // staging slot constants (computed once)
  int sx1 = t, sx2 = t + 256;
  int tk1 = sx1 >> 4, jp1 = sx1 & 15;
  int tk2 = sx2 >> 4, jp2 = sx2 & 15;
  const float* xsrc1 = x + (size_t)(n0 + tk1) * DIM + 4 * (jp1 ^ (tk1 & 7));
  const float* xsrc2 = x + (size_t)(n0 + tk2) * DIM + 4 * (jp2 ^ (tk2 & 7));
  int wgk = t >> 1, wgh = t & 1;          // slot t of wG: t<128 wg, else wn
  const float* wgsrc = (t < 128) ? (wg + (size_t)wgk * NE + (wgh << 2))
                                 : (wn + (size_t)(wgk - 64) * NE + (wgh << 2));

  #define STAGE(C, HALF) { \
    size_t kc = (size_t)(C) * KC; \
    char* xb_ = smem + XB_OFF + (HALF) * 8192; \
    char* wA_ = smem + WA_OFF + (HALF) * 32768; \
    char* wG_ = smem + WG_OFF + (HALF) * 4096; \
    stage16(xsrc1 + kc, xb_ + sx1 * 16); \
    stage16(xsrc2 + kc, xb_ + sx2 * 16); \
    _Pragma("unroll") \
    for (int i = 0; i < 8; ++i) { \
      int s = t + (i << 8); int col = s >> 4, jp = s & 15; \
      stage16(la + (size_t)col * DIM + kc + 4 * (jp ^ ((col >> 2) & 7)), wA_ + s * 16); \
    } \
    stage16(wgsrc + kc * NE, wG_ + t * 16); \
  }

  STAGE(0, 0)
  waitvm0();
  __syncthreads();

  for (int c = 0; c < NCH; ++c) {
    int half = c & 1;
    if (c + 1 < NCH) STAGE(c + 1, half ^ 1)
    const char* xb_ = smem + XB_OFF + half * 8192;
    const char* wA_ = smem + WA_OFF + half * 32768;
    const char* wG_ = smem + WG_OFF + half * 4096 + ((og & 4) ? 2048 : 0) + ((og & 3) << 3);
    int tA0 = (tokg << 2);
    #pragma unroll
    for (int j = 0; j < 16; ++j) {
      // phase A
      float4 xv0 = *(const float4*)(xb_ + (tA0 + 0) * 256 + ((j ^ ((tA0 + 0) & 7)) << 4));
      float4 xv1 = *(const float4*)(xb_ + (tA0 + 1) * 256 + ((j ^ ((tA0 + 1) & 7)) << 4));
      float4 xv2 = *(const float4*)(xb_ + (tA0 + 2) * 256 + ((j ^ ((tA0 + 2) & 7)) << 4));
      float4 xv3 = *(const float4*)(xb_ + (tA0 + 3) * 256 + ((j ^ ((tA0 + 3) & 7)) << 4));
      int jw = (j ^ (colq & 7)) << 4;
      float4 wv0 = *(const float4*)(wA_ + ((colq << 2) + 0) * 256 + jw);
      float4 wv1 = *(const float4*)(wA_ + ((colq << 2) + 1) * 256 + jw);
      float4 wv2 = *(const float4*)(wA_ + ((colq << 2) + 2) * 256 + jw);
      float4 wv3 = *(const float4*)(wA_ + ((colq << 2) + 3) * 256 + jw);
      DOT4ACC(acc0.x, xv0, wv0); DOT4ACC(acc0.y, xv0, wv1); DOT4ACC(acc0.z, xv0, wv2); DOT4ACC(acc0.w, xv0, wv3);
      DOT4ACC(acc1.x, xv1, wv0); DOT4ACC(acc1.y, xv1, wv1); DOT4ACC(acc1.z, xv1, wv2); DOT4ACC(acc1.w, xv1, wv3);
      DOT4ACC(acc2.x, xv2, wv0); DOT4ACC(acc2.y, xv2, wv1); DOT4ACC(acc2.z, xv2, wv2); DOT4ACC(acc2.w, xv2, wv3);
      DOT4ACC(acc3.x, xv3, wv0); DOT4ACC(acc3.y, xv3, wv1); DOT4ACC(acc3.z, xv3, wv2); DOT4ACC(acc3.w, xv3, wv3);
      // phase B (gating): 4 k values
      float4 xvB = *(const float4*)(xb_ + tokB * 256 + ((j ^ (tokB & 7)) << 4));
      float2 w0 = *(const float2*)(wG_ + ((4 * j + 0) << 5));
      float2 w1 = *(const float2*)(wG_ + ((4 * j + 1) << 5));
      float2 w2 = *(const float2*)(wG_ + ((4 * j + 2) << 5));
      float2 w3 = *(const float2*)(wG_ + ((4 * j + 3) << 5));
      ga = fmaf(xvB.x, w0.x, ga); gb = fmaf(xvB.x, w0.y, gb);
      ga = fmaf(xvB.y, w1.x, ga); gb = fmaf(xvB.y, w1.y, gb);
      ga = fmaf(xvB.z, w2.x, ga); gb = fmaf(xvB.z, w2.y, gb);
      ga = fmaf(xvB.w, w3.x, ga); gb = fmaf(xvB.w, w3.y, gb);
    }
    if (c + 1 < NCH) { waitvm0(); __syncthreads(); }
  }
  // gating logits to LDS: col index = 2og (og<4: gate 0..7; og>=4: noise 8..15)
  lgS[tokB * 20 + 2 * og]     = ga;
  lgS[tokB * 20 + 2 * og + 1] = gb;
  __syncthreads();
  if (t < 32) {
    int n = n0 + t;
    float cl[8], st[8], lg[8];
    float4 nzv0 = *(const float4*)(nz + (size_t)n * NE);
    float4 nzv1 = *(const float4*)(nz + (size_t)n * NE + 4);
    float nzv[8] = {nzv0.x, nzv0.y, nzv0.z, nzv0.w, nzv1.x, nzv1.y, nzv1.z, nzv1.w};
    #pragma unroll
    for (int e = 0; e < 8; ++e) cl[e] = lgS[t * 20 + e];
    #pragma unroll
    for (int e = 0; e < 8; ++e) {
      st[e] = softplusf(lgS[t * 20 + 8 + e]) + 0.01f;
      lg[e] = fmaf(nzv[e], st[e], cl[e]);
    }
    float m1 = -1e30f, m2 = -1e30f; int idx = 0;
    #pragma unroll
    for (int e = 0; e < 8; ++e) {
      float v = lg[e];
      if (v > m1)      { m2 = m1; m1 = v; idx = e; }
      else if (v > m2) { m2 = v; }
    }
    eid[n] = idx;
    eid_sh[t] = idx;
    float pr[8], cw[8];
    #pragma unroll
    for (int e = 0; e < 8; ++e) {
      float thr = (lg[e] > m2) ? m2 : m1;
      pr[e] = ncdf((cl[e] - thr) / st[e]);
    }
    #pragma unroll
    for (int e = 0; e < 8; ++e) cw[e] = (float)__popcll(__ballot(idx == e));
    #pragma unroll
    for (int e = 0; e < 8; ++e) {
      #pragma unroll
      for (int off = 1; off <= 16; off <<= 1) pr[e] += __shfl_xor(pr[e], off);
    }
    if (t == 0) {
      #pragma unroll
      for (int e = 0; e < 8; ++e) {
        part[blockIdx.x * 16 + e]     = cw[e];
        part[blockIdx.x * 16 + 8 + e] = pr[e];
      }
    }
  }
  __syncthreads();
  // write h only for the selected expert of each token (compact [n][16])
  int myE = colq >> 2, rq = (colq & 3) << 2;
  int tA0 = tokg << 2;
  if (eid_sh[tA0 + 0] == myE) *(float4*)(h + (size_t)(n0 + tA0 + 0) * NR + rq) = acc0;
  if (eid_sh[tA0 + 1] == myE) *(float4*)(h + (size_t)(n0 + tA0 + 1) * NR + rq) = acc1;
  if (eid_sh[tA0 + 2] == myE) *(float4*)(h + (size_t)(n0 + tA0 + 2) * NR + rq) = acc2;
  if (eid_sh[tA0 + 3] == myE) *(float4*)(h + (size_t)(n0 + tA0 + 3) * NR + rq) = acc3;
  #undef STAGE
}

// ---------------------------------------------------------------------------
// kC: counts from partials (fused kB, redundant per block) + bucket scatter.
// 32 blocks x 256. Block 0 also writes importance/load to d_out tail.
// ---------------------------------------------------------------------------
__global__ __launch_bounds__(256) void kC(const float* __restrict__ part,
    const int* __restrict__ eid, int* __restrict__ fill, int* __restrict__ bucket,
    float* __restrict__ outIL, int* __restrict__ counts) {
  __shared__ float red[16][16];
  __shared__ int cnt_s[8], lcnt[8], lbase[8];
  int t = threadIdx.x;
  int s = t & 15, g = t >> 4;
  float sum = 0.f;
  #pragma unroll
  for (int j = 0; j < 16; ++j) sum += part[(g + 16 * j) * 16 + s];
  red[g][s] = sum;
  if (t < 8) lcnt[t] = 0;
  __syncthreads();
  if (t < 16) {
    float tot = 0.f;
    #pragma unroll
    for (int gg = 0; gg < 16; ++gg) tot += red[gg][t];
    if (blockIdx.x == 0) outIL[t] = tot;
    if (t < 8) {
      cnt_s[t] = (int)(tot + 0.5f);
      if (blockIdx.x == 0) counts[t] = (int)(tot + 0.5f);
    }
  }
  __syncthreads();
  int n = blockIdx.x * 256 + t;
  int e = eid[n];
  int rank = atomicAdd(&lcnt[e], 1);
  __syncthreads();
  if (t < 8) lbase[t] = atomicAdd(&fill[t], lcnt[t]);
  __syncthreads();
  int off = 0;
  #pragma unroll
  for (int i = 0; i < 8; ++i) if (i < e) off += cnt_s[i];
  bucket[off + lbase[e] + rank] = n;
}

// ---------------------------------------------------------------------------
// kE: out[n] = lora_b[e] @ h[n]. Tiles: 64 tokens x 256 outs. h gathered by
// raw token id (unsorted compact h).
// ---------------------------------------------------------------------------
__global__ __launch_bounds__(256) void kE(const float* __restrict__ h,
    const float* __restrict__ lb, const int* __restrict__ counts,
    const int* __restrict__ bucket, float* __restrict__ out) {
  __shared__ float bt[16][260];
  __shared__ float ht[16][64];
  __shared__ int toks[64];
  int tile = blockIdx.y;
  int e = -1, jt = 0, off = 0;
  { int tot = 0, o = 0;
    #pragma unroll
    for (int i = 0; i < 8; ++i) {
      int c = counts[i]; int nt = (c + 63) >> 6;
      if (e < 0 && tile < tot + nt) { e = i; jt = tile - tot; off = o; }
      tot += nt; o += c;
    } }
  if (e < 0) return;
  int cnt = counts[e];
  int p0 = off + (jt << 6);
  int valid = min(64, cnt - (jt << 6));
  int o0 = blockIdx.x << 8;
  int t = threadIdx.x;
  if (t < 64) toks[t] = bucket[p0 + min(t, valid - 1)];
  __syncthreads();
  const float* bbase = lb + ((size_t)e * NO + o0) * NR;
  #pragma unroll
  for (int kk = 0; kk < 4; ++kk) {
    int idx = (kk << 8) + t;
    int o = idx >> 2, rq = (idx & 3) << 2;
    float4 v = *(const float4*)(bbase + o * NR + rq);
    bt[rq + 0][o] = v.x; bt[rq + 1][o] = v.y; bt[rq + 2][o] = v.z; bt[rq + 3][o] = v.w;
  }
  { int tok = t >> 2, rq = (t & 3) << 2;
    float4 v = *(const float4*)(h + (size_t)toks[tok] * NR + rq);
    ht[rq + 0][tok] = v.x; ht[rq + 1][tok] = v.y; ht[rq + 2][tok] = v.z; ht[rq + 3][tok] = v.w; }
  __syncthreads();
  int og = t & 31, tokg = t >> 5;
  int ob = og << 2, tb = tokg << 3;
  float4 z = Z4;
  float4 aL0=z,aL1=z,aL2=z,aL3=z,aL4=z,aL5=z,aL6=z,aL7=z;
  float4 aH0=z,aH1=z,aH2=z,aH3=z,aH4=z,aH5=z,aH6=z,aH7=z;
  #pragma unroll
  for (int r = 0; r < 16; ++r) {
    float4 blo = *(const float4*)&bt[r][ob];
    float4 bhi = *(const float4*)&bt[r][ob + 128];
    float4 h0  = *(const float4*)&ht[r][tb];
    float4 h1  = *(const float4*)&ht[r][tb + 4];
    FMA4(aL0, h0.x, blo); FMA4(aH0, h0.x, bhi);
    FMA4(aL1, h0.y, blo); FMA4(aH1, h0.y, bhi);
    FMA4(aL2, h0.z, blo); FMA4(aH2, h0.z, bhi);
    FMA4(aL3, h0.w, blo); FMA4(aH3, h0.w, bhi);
    FMA4(aL4, h1.x, blo); FMA4(aH4, h1.x, bhi);
    FMA4(aL5, h1.y, blo); FMA4(aH5, h1.y, bhi);
    FMA4(aL6, h1.z, blo); FMA4(aH6, h1.z, bhi);
    FMA4(aL7, h1.w, blo); FMA4(aH7, h1.w, bhi);
  }
  #define ST(J, AL, AH) { int tt = tb + (J); if (tt < valid) { \
      float* p = out + (size_t)toks[tt] * NO + o0 + ob; \
      *(float4*)p = AL; *(float4*)(p + 128) = AH; } }
  ST(0, aL0, aH0); ST(1, aL1, aH1); ST(2, aL2, aH2); ST(3, aL3, aH3);
  ST(4, aL4, aH4); ST(5, aL5, aH5); ST(6, aL6, aH6); ST(7, aL7, aH7);
  #undef ST
}

// ---------------------------------------------------------------------------
extern "C" void kernel_launch(void* const* d_in, const int* in_sizes, int n_in,
                              void* d_out, int out_size, void* d_ws, size_t ws_size,
                              hipStream_t stream) {
  const float* x  = (const float*)d_in[0];
  const float* wg = (const float*)d_in[1];
  const float* wn = (const float*)d_in[2];
  const float* la = (const float*)d_in[3];
  const float* lb = (const float*)d_in[4];
  const float* nz = (const float*)d_in[5];
  float* out = (float*)d_out;

  char* ws = (char*)d_ws;
  float* h        = (float*)(ws);                 // 524288 B
  int*   eid      = (int*)  (ws + 524288);        // 32768 B
  int*   bucket   = (int*)  (ws + 557056);        // 32768 B
  float* partials = (float*)(ws + 589824);        // 16384 B
  int*   counts   = (int*)  (ws + 606208);        // 32 B
  int*   fill     = (int*)  (ws + 606240);        // 32 B

  hipFuncSetAttribute((const void*)kF, hipFuncAttributeMaxDynamicSharedMemorySize, KF_SMEM);
  hipMemsetAsync(fill, 0, 32, stream);
  kF<<<256, 256, KF_SMEM, stream>>>(x, wg, wn, la, nz, eid, partials, h);
  kC<<<32, 256, 0, stream>>>(partials, eid, fill, bucket, out + OUT_ELEMS, counts);
  kE<<<dim3(12, 135), 256, 0, stream>>>(h, lb, counts, bucket, out);
}

// Round 8
// 83.296 us; speedup vs baseline: 6.0852x; 6.0852x over previous
//
#include <hip/hip_runtime.h>
#include <math.h>

#define N_TOK 8192
#define DIM   1024
#define NE    8
#define NR    16
#define NO    3072
#define OUT_ELEMS (N_TOK * NO)   // 25165824

__device__ __forceinline__ float softplusf(float z) {
  return z > 0.f ? z + log1pf(expf(-z)) : log1pf(expf(z));
}
__device__ __forceinline__ float ncdf(float z) {
  return 0.5f * erfcf(-z * 0.70710678118654752f);
}

#define FMA4(A, S, W) { (A).x = fmaf((S),(W).x,(A).x); (A).y = fmaf((S),(W).y,(A).y); \
                        (A).z = fmaf((S),(W).z,(A).z); (A).w = fmaf((S),(W).w,(A).w); }
#define Z4 make_float4(0.f,0.f,0.f,0.f)

// quad cross-lane add via DPP (VALU pipe): xor1=quad_perm[1,0,3,2]=0xB1, xor2=[2,3,0,1]=0x4E
#define DPP_ADD(V, CTRL) ((V) + __int_as_float(__builtin_amdgcn_update_dpp(0, __float_as_int(V), (CTRL), 0xf, 0xf, true)))
#define QRED4(A) { (A).x = DPP_ADD((A).x, 0xB1); (A).y = DPP_ADD((A).y, 0xB1); \
                   (A).z = DPP_ADD((A).z, 0xB1); (A).w = DPP_ADD((A).w, 0xB1); \
                   (A).x = DPP_ADD((A).x, 0x4E); (A).y = DPP_ADD((A).y, 0x4E); \
                   (A).z = DPP_ADD((A).z, 0x4E); (A).w = DPP_ADD((A).w, 0x4E); }

typedef __attribute__((address_space(3))) void LDSV;
typedef const __attribute__((address_space(1))) void GLBV;
__device__ __forceinline__ void stage16(const void* g, void* l) {
  __builtin_amdgcn_global_load_lds((GLBV*)g, (LDSV*)l, 16, 0, 0);
}
__device__ __forceinline__ void waitvm0() {
  asm volatile("s_waitcnt vmcnt(0)" ::: "memory");
}

// kA LDS: wgl 32K | wnl 32K | pd[2][64][16] 8K | lgS[16][17] 1088
#define KA_SMEM (65536 + 8192 + 1088)
// kD LDS: lal 64K | pd 8K | hS 1088 | toks 64
#define KD_SMEM (65536 + 8192 + 1088 + 64)

// ---------------------------------------------------------------------------
// kA: gating GEMV. 16 tokens/block x 512 blocks, 2 blocks/CU.
// wg/wn staged LINEARLY to LDS via global_load_lds (coalesced), then one-time
// LDS->reg fill (conflicts bounded, once). Per token: 64 FMA + DPP quad-
// reduce -> pd dump; per 2-token round: stage-2 transpose-reduce -> lgS.
// Epilogue (t<16): softplus/top-2/ncdf/partials.
// ---------------------------------------------------------------------------
__global__ __launch_bounds__(256, 2) void kA(const float* __restrict__ x,
    const float* __restrict__ wg, const float* __restrict__ wn,
    const float* __restrict__ nz, int* __restrict__ eid, float* __restrict__ part) {
  extern __shared__ char smem[];
  float* wgl = (float*)smem;                    // [1024][8]
  float* wnl = (float*)(smem + 32768);          // [1024][8]
  float* pdf = (float*)(smem + 65536);          // [2][64][16]
  float* lgS = (float*)(smem + 65536 + 8192);   // [16][17]
  int t = threadIdx.x;
  int n0 = blockIdx.x << 4;
  int qd = t >> 2, l2 = t & 3, wid = t >> 6, lane = t & 63;
  // stage both weight matrices, fully coalesced (32 KB each)
  #pragma unroll
  for (int i = 0; i < 8; ++i) {
    int s = (i << 8) + t;                       // float4 slot
    stage16(wg + ((size_t)s << 2), (char*)wgl + s * 16);
    stage16(wn + ((size_t)s << 2), (char*)wnl + s * 16);
  }
  waitvm0();
  __syncthreads();
  // one-time reg fill: thread t owns d=[4t,4t+4); native [d][8] layout
  float4 g0a = *(const float4*)&wgl[((t << 2) + 0) * NE + 0], g0b = *(const float4*)&wgl[((t << 2) + 0) * NE + 4];
  float4 g1a = *(const float4*)&wgl[((t << 2) + 1) * NE + 0], g1b = *(const float4*)&wgl[((t << 2) + 1) * NE + 4];
  float4 g2a = *(const float4*)&wgl[((t << 2) + 2) * NE + 0], g2b = *(const float4*)&wgl[((t << 2) + 2) * NE + 4];
  float4 g3a = *(const float4*)&wgl[((t << 2) + 3) * NE + 0], g3b = *(const float4*)&wgl[((t << 2) + 3) * NE + 4];
  float4 q0a = *(const float4*)&wnl[((t << 2) + 0) * NE + 0], q0b = *(const float4*)&wnl[((t << 2) + 0) * NE + 4];
  float4 q1a = *(const float4*)&wnl[((t << 2) + 1) * NE + 0], q1b = *(const float4*)&wnl[((t << 2) + 1) * NE + 4];
  float4 q2a = *(const float4*)&wnl[((t << 2) + 2) * NE + 0], q2b = *(const float4*)&wnl[((t << 2) + 2) * NE + 4];
  float4 q3a = *(const float4*)&wnl[((t << 2) + 3) * NE + 0], q3b = *(const float4*)&wnl[((t << 2) + 3) * NE + 4];
  const float* xb = x + (size_t)n0 * DIM + (t << 2);
  float4 xc0 = *(const float4*)(xb + 0 * DIM);
  float4 xc1 = *(const float4*)(xb + 1 * DIM);
  #define TOKEN(K, XC) { \
    float4 aA = Z4, aB = Z4, aC = Z4, aD = Z4; \
    FMA4(aA, (XC).x, g0a); FMA4(aB, (XC).x, g0b); FMA4(aC, (XC).x, q0a); FMA4(aD, (XC).x, q0b); \
    FMA4(aA, (XC).y, g1a); FMA4(aB, (XC).y, g1b); FMA4(aC, (XC).y, q1a); FMA4(aD, (XC).y, q1b); \
    FMA4(aA, (XC).z, g2a); FMA4(aB, (XC).z, g2b); FMA4(aC, (XC).z, q2a); FMA4(aD, (XC).z, q2b); \
    FMA4(aA, (XC).w, g3a); FMA4(aB, (XC).w, g3b); FMA4(aC, (XC).w, q3a); FMA4(aD, (XC).w, q3b); \
    QRED4(aA); QRED4(aB); QRED4(aC); QRED4(aD); \
    if (l2 == 0) { \
      float* p_ = pdf + ((((K) << 6) + qd) << 4); \
      *(float4*)(p_ + 0) = aA; *(float4*)(p_ + 4)  = aB; \
      *(float4*)(p_ + 8) = aC; *(float4*)(p_ + 12) = aD; } }
  for (int r = 0; r < 8; ++r) {
    float4 xn0, xn1;
    if (r < 7) {
      xn0 = *(const float4*)(xb + (size_t)((r << 1) + 2) * DIM);
      xn1 = *(const float4*)(xb + (size_t)((r << 1) + 3) * DIM);
    }
    TOKEN(0, xc0)
    TOKEN(1, xc1)
    __syncthreads();
    if (wid < 2) {
      int o = lane >> 2, r2 = lane & 3;
      float s2 = 0.f;
      #pragma unroll
      for (int j = 0; j < 16; ++j) s2 += pdf[((wid << 6) + (j << 2) + r2) * 16 + o];
      s2 = DPP_ADD(s2, 0xB1); s2 = DPP_ADD(s2, 0x4E);
      if (r2 == 0) lgS[((r << 1) + wid) * 17 + o] = s2;
    }
    __syncthreads();
    xc0 = xn0; xc1 = xn1;
  }
  #undef TOKEN
  if (t < 16) {
    int n = n0 + t;
    float cl[8], st[8], lg[8];
    float4 nzv0 = *(const float4*)(nz + (size_t)n * NE);
    float4 nzv1 = *(const float4*)(nz + (size_t)n * NE + 4);
    float nzv[8] = {nzv0.x, nzv0.y, nzv0.z, nzv0.w, nzv1.x, nzv1.y, nzv1.z, nzv1.w};
    #pragma unroll
    for (int e = 0; e < 8; ++e) cl[e] = lgS[t * 17 + e];
    #pragma unroll
    for (int e = 0; e < 8; ++e) {
      st[e] = softplusf(lgS[t * 17 + 8 + e]) + 0.01f;
      lg[e] = fmaf(nzv[e], st[e], cl[e]);
    }
    float m1 = -1e30f, m2 = -1e30f; int idx = 0;
    #pragma unroll
    for (int e = 0; e < 8; ++e) {
      float v = lg[e];
      if (v > m1)      { m2 = m1; m1 = v; idx = e; }
      else if (v > m2) { m2 = v; }
    }
    eid[n] = idx;
    float pr[8], cw[8];
    #pragma unroll
    for (int e = 0; e < 8; ++e) {
      float thr = (lg[e] > m2) ? m2 : m1;
      pr[e] = ncdf((cl[e] - thr) / st[e]);
    }
    #pragma unroll
    for (int e = 0; e < 8; ++e) cw[e] = (float)__popcll(__ballot(idx == e));
    #pragma unroll
    for (int e = 0; e < 8; ++e) {
      #pragma unroll
      for (int off = 1; off <= 8; off <<= 1) pr[e] += __shfl_xor(pr[e], off);
    }
    if (t == 0) {
      #pragma unroll
      for (int e = 0; e < 8; ++e) {
        part[blockIdx.x * 16 + e]     = cw[e];
        part[blockIdx.x * 16 + 8 + e] = pr[e];
      }
    }
  }
}

// ---------------------------------------------------------------------------
// kC: fused counts reduction (512x16 partials) + bucket scatter. 32 blocks.
// Block 0 writes importance/load (d_out tail) and counts.
// ---------------------------------------------------------------------------
__global__ __launch_bounds__(256) void kC(const float* __restrict__ part,
    const int* __restrict__ eid, int* __restrict__ fill, int* __restrict__ bucket,
    float* __restrict__ outIL, int* __restrict__ counts) {
  __shared__ float red[16][16];
  __shared__ int cnt_s[8], lcnt[8], lbase[8];
  int t = threadIdx.x;
  int s = t & 15, g = t >> 4;
  float sum = 0.f;
  #pragma unroll
  for (int j = 0; j < 32; ++j) sum += part[(g + 16 * j) * 16 + s];
  red[g][s] = sum;
  if (t < 8) lcnt[t] = 0;
  __syncthreads();
  if (t < 16) {
    float tot = 0.f;
    #pragma unroll
    for (int gg = 0; gg < 16; ++gg) tot += red[gg][t];
    if (blockIdx.x == 0) outIL[t] = tot;
    if (t < 8) {
      cnt_s[t] = (int)(tot + 0.5f);
      if (blockIdx.x == 0) counts[t] = (int)(tot + 0.5f);
    }
  }
  __syncthreads();
  int n = blockIdx.x * 256 + t;
  int e = eid[n];
  int rank = atomicAdd(&lcnt[e], 1);
  __syncthreads();
  if (t < 8) lbase[t] = atomicAdd(&fill[t], lcnt[t]);
  __syncthreads();
  int off = 0;
  #pragma unroll
  for (int i = 0; i < 8; ++i) if (i < e) off += cnt_s[i];
  bucket[off + lbase[e] + rank] = n;
}

// ---------------------------------------------------------------------------
// kD: h_sorted[p] = lora_a[e] @ x[bucket[p]], 16 tokens/tile, 519 blocks.
// la[e] staged LINEARLY to LDS (coalesced stage16), one-time LDS->reg fill
// of 16 r-row float4 slices; DPP quad-reduce + pd transpose stage-2.
// ---------------------------------------------------------------------------
__global__ __launch_bounds__(256, 2) void kD(const float* __restrict__ x,
    const float* __restrict__ la, const int* __restrict__ counts,
    const int* __restrict__ bucket, float* __restrict__ h) {
  extern __shared__ char smem[];
  float* lal = (float*)smem;                    // [16][1024]
  float* pdf = (float*)(smem + 65536);          // [2][64][16]
  float* hS  = (float*)(smem + 65536 + 8192);   // [16][17]
  int*  toks = (int*)(smem + 65536 + 8192 + 1088);
  int tile = blockIdx.x;
  int e = -1, jt = 0, off = 0;
  { int tot = 0, o = 0;
    #pragma unroll
    for (int i = 0; i < 8; ++i) {
      int c = counts[i]; int nt = (c + 15) >> 4;
      if (e < 0 && tile < tot + nt) { e = i; jt = tile - tot; off = o; }
      tot += nt; o += c;
    } }
  if (e < 0) return;
  int cnt = counts[e];
  int p0 = off + (jt << 4);
  int valid = min(16, cnt - (jt << 4));
  int t = threadIdx.x;
  if (t < 16) toks[t] = bucket[p0 + min(t, valid - 1)];
  #pragma unroll
  for (int i = 0; i < 16; ++i) {
    int s = (i << 8) + t;
    stage16(la + (size_t)e * (NR * DIM) + ((size_t)s << 2), (char*)lal + s * 16);
  }
  waitvm0();
  __syncthreads();
  int qd = t >> 2, l2 = t & 3, wid = t >> 6, lane = t & 63;
  float4 w0  = *(const float4*)&lal[0  * DIM + (t << 2)];
  float4 w1  = *(const float4*)&lal[1  * DIM + (t << 2)];
  float4 w2  = *(const float4*)&lal[2  * DIM + (t << 2)];
  float4 w3  = *(const float4*)&lal[3  * DIM + (t << 2)];
  float4 w4  = *(const float4*)&lal[4  * DIM + (t << 2)];
  float4 w5  = *(const float4*)&lal[5  * DIM + (t << 2)];
  float4 w6  = *(const float4*)&lal[6  * DIM + (t << 2)];
  float4 w7  = *(const float4*)&lal[7  * DIM + (t << 2)];
  float4 w8  = *(const float4*)&lal[8  * DIM + (t << 2)];
  float4 w9  = *(const float4*)&lal[9  * DIM + (t << 2)];
  float4 w10 = *(const float4*)&lal[10 * DIM + (t << 2)];
  float4 w11 = *(const float4*)&lal[11 * DIM + (t << 2)];
  float4 w12 = *(const float4*)&lal[12 * DIM + (t << 2)];
  float4 w13 = *(const float4*)&lal[13 * DIM + (t << 2)];
  float4 w14 = *(const float4*)&lal[14 * DIM + (t << 2)];
  float4 w15 = *(const float4*)&lal[15 * DIM + (t << 2)];
  int dof = t << 2;
  float4 xc0 = *(const float4*)(x + (size_t)toks[0] * DIM + dof);
  float4 xc1 = *(const float4*)(x + (size_t)toks[1] * DIM + dof);
  #define DOTC(ACC, W, XC) ACC = fmaf((XC).x,(W).x, fmaf((XC).y,(W).y, fmaf((XC).z,(W).z, fmaf((XC).w,(W).w,(ACC)))))
  #define TOKEN(K, XC) { \
    float4 aA = Z4, aB = Z4, aC = Z4, aD = Z4; \
    DOTC(aA.x, w0, XC);  DOTC(aA.y, w1, XC);  DOTC(aA.z, w2, XC);  DOTC(aA.w, w3, XC); \
    DOTC(aB.x, w4, XC);  DOTC(aB.y, w5, XC);  DOTC(aB.z, w6, XC);  DOTC(aB.w, w7, XC); \
    DOTC(aC.x, w8, XC);  DOTC(aC.y, w9, XC);  DOTC(aC.z, w10, XC); DOTC(aC.w, w11, XC); \
    DOTC(aD.x, w12, XC); DOTC(aD.y, w13, XC); DOTC(aD.z, w14, XC); DOTC(aD.w, w15, XC); \
    QRED4(aA); QRED4(aB); QRED4(aC); QRED4(aD); \
    if (l2 == 0) { \
      float* p_ = pdf + ((((K) << 6) + qd) << 4); \
      *(float4*)(p_ + 0) = aA; *(float4*)(p_ + 4)  = aB; \
      *(float4*)(p_ + 8) = aC; *(float4*)(p_ + 12) = aD; } }
  for (int r = 0; r < 8; ++r) {
    float4 xn0, xn1;
    if (r < 7) {
      xn0 = *(const float4*)(x + (size_t)toks[(r << 1) + 2] * DIM + dof);
      xn1 = *(const float4*)(x + (size_t)toks[(r << 1) + 3] * DIM + dof);
    }
    TOKEN(0, xc0)
    TOKEN(1, xc1)
    __syncthreads();
    if (wid < 2) {
      int o = lane >> 2, r2 = lane & 3;
      float s2 = 0.f;
      #pragma unroll
      for (int j = 0; j < 16; ++j) s2 += pdf[((wid << 6) + (j << 2) + r2) * 16 + o];
      s2 = DPP_ADD(s2, 0xB1); s2 = DPP_ADD(s2, 0x4E);
      if (r2 == 0) hS[((r << 1) + wid) * 17 + o] = s2;
    }
    __syncthreads();
    xc0 = xn0; xc1 = xn1;
  }
  #undef TOKEN
  #undef DOTC
  if (t < 64) {
    int tok = t >> 2, rq = (t & 3) << 2;
    if (tok < valid) {
      float4 v = make_float4(hS[tok * 17 + rq + 0], hS[tok * 17 + rq + 1],
                             hS[tok * 17 + rq + 2], hS[tok * 17 + rq + 3]);
      *(float4*)(h + (size_t)(p0 + tok) * NR + rq) = v;
    }
  }
}

// ---------------------------------------------------------------------------
// kE: out[n] = lora_b[e] @ h_sorted. Tiles: 64 tokens x 256 outs.
// ---------------------------------------------------------------------------
__global__ __launch_bounds__(256) void kE(const float* __restrict__ h,
    const float* __restrict__ lb, const int* __restrict__ counts,
    const int* __restrict__ bucket, float* __restrict__ out) {
  __shared__ float bt[16][260];
  __shared__ float ht[16][64];
  __shared__ int toks[64];
  int tile = blockIdx.y;
  int e = -1, jt = 0, off = 0;
  { int tot = 0, o = 0;
    #pragma unroll
    for (int i = 0; i < 8; ++i) {
      int c = counts[i]; int nt = (c + 63) >> 6;
      if (e < 0 && tile < tot + nt) { e = i; jt = tile - tot; off = o; }
      tot += nt; o += c;
    } }
  if (e < 0) return;
  int cnt = counts[e];
  int p0 = off + (jt << 6);
  int valid = min(64, cnt - (jt << 6));
  int o0 = blockIdx.x << 8;
  int t = threadIdx.x;
  if (t < 64) toks[t] = bucket[p0 + min(t, valid - 1)];
  const float* bbase = lb + ((size_t)e * NO + o0) * NR;
  #pragma unroll
  for (int kk = 0; kk < 4; ++kk) {
    int idx = (kk << 8) + t;
    int o = idx >> 2, rq = (idx & 3) << 2;
    float4 v = *(const float4*)(bbase + o * NR + rq);
    bt[rq + 0][o] = v.x; bt[rq + 1][o] = v.y; bt[rq + 2][o] = v.z; bt[rq + 3][o] = v.w;
  }
  { int tok = t >> 2, rq = (t & 3) << 2;
    float4 v = *(const float4*)(h + (size_t)(p0 + min(tok, valid - 1)) * NR + rq);
    ht[rq + 0][tok] = v.x; ht[rq + 1][tok] = v.y; ht[rq + 2][tok] = v.z; ht[rq + 3][tok] = v.w; }
  __syncthreads();
  int og = t & 31, tokg = t >> 5;
  int ob = og << 2, tb = tokg << 3;
  float4 z = Z4;
  float4 aL0=z,aL1=z,aL2=z,aL3=z,aL4=z,aL5=z,aL6=z,aL7=z;
  float4 aH0=z,aH1=z,aH2=z,aH3=z,aH4=z,aH5=z,aH6=z,aH7=z;
  #pragma unroll
  for (int r = 0; r < 16; ++r) {
    float4 blo = *(const float4*)&bt[r][ob];
    float4 bhi = *(const float4*)&bt[r][ob + 128];
    float4 h0  = *(const float4*)&ht[r][tb];
    float4 h1  = *(const float4*)&ht[r][tb + 4];
    FMA4(aL0, h0.x, blo); FMA4(aH0, h0.x, bhi);
    FMA4(aL1, h0.y, blo); FMA4(aH1, h0.y, bhi);
    FMA4(aL2, h0.z, blo); FMA4(aH2, h0.z, bhi);
    FMA4(aL3, h0.w, blo); FMA4(aH3, h0.w, bhi);
    FMA4(aL4, h1.x, blo); FMA4(aH4, h1.x, bhi);
    FMA4(aL5, h1.y, blo); FMA4(aH5, h1.y, bhi);
    FMA4(aL6, h1.z, blo); FMA4(aH6, h1.z, bhi);
    FMA4(aL7, h1.w, blo); FMA4(aH7, h1.w, bhi);
  }
  #define ST(J, AL, AH) { int tt = tb + (J); if (tt < valid) { \
      float* p = out + (size_t)toks[tt] * NO + o0 + ob; \
      *(float4*)p = AL; *(float4*)(p + 128) = AH; } }
  ST(0, aL0, aH0); ST(1, aL1, aH1); ST(2, aL2, aH2); ST(3, aL3, aH3);
  ST(4, aL4, aH4); ST(5, aL5, aH5); ST(6, aL6, aH6); ST(7, aL7, aH7);
  #undef ST
}

// ---------------------------------------------------------------------------
extern "C" void kernel_launch(void* const* d_in, const int* in_sizes, int n_in,
                              void* d_out, int out_size, void* d_ws, size_t ws_size,
                              hipStream_t stream) {
  const float* x  = (const float*)d_in[0];
  const float* wg = (const float*)d_in[1];
  const float* wn = (const float*)d_in[2];
  const float* la = (const float*)d_in[3];
  const float* lb = (const float*)d_in[4];
  const float* nz = (const float*)d_in[5];
  float* out = (float*)d_out;

  char* ws = (char*)d_ws;
  float* h        = (float*)(ws);                 // 524288 B
  int*   eid      = (int*)  (ws + 524288);        // 32768 B
  int*   bucket   = (int*)  (ws + 557056);        // 32768 B
  float* partials = (float*)(ws + 589824);        // 32768 B (512*16*4)
  int*   counts   = (int*)  (ws + 622592);        // 32 B
  int*   fill     = (int*)  (ws + 622624);        // 32 B

  hipFuncSetAttribute((const void*)kA, hipFuncAttributeMaxDynamicSharedMemorySize, KA_SMEM);
  hipFuncSetAttribute((const void*)kD, hipFuncAttributeMaxDynamicSharedMemorySize, KD_SMEM);
  hipMemsetAsync(fill, 0, 32, stream);
  kA<<<512, 256, KA_SMEM, stream>>>(x, wg, wn, nz, eid, partials);
  kC<<<32, 256, 0, stream>>>(partials, eid, fill, bucket, out + OUT_ELEMS, counts);
  kD<<<519, 256, KD_SMEM, stream>>>(x, la, counts, bucket, h);
  kE<<<dim3(12, 135), 256, 0, stream>>>(h, lb, counts, bucket, out);
}